// Round 1
// baseline (243.505 us; speedup 1.0000x reference)
//
#include <hip/hip_runtime.h>

// Parametric LIF forward (spike output only).
// x: [B=64, T=64, N=8192] fp32.  out: same shape, values in {0,1}.
// Recurrence per (b,n):  u = last*sig + x[t];  s = (u >= th);
//                        last = (u + lamb*(u-last)) * (1-s)
// Independent across (b,n) -> one thread per 4 n-values (float4), loop over t.
// All FP ops via *_rn intrinsics to forbid FMA contraction and match the
// numpy reference bit-for-bit (spike output is {0,1}; any flip = absmax 1).

#define LIF_B 64
#define LIF_T 64
#define LIF_N 8192
#define NV (LIF_N / 4)   // float4s per row

__global__ __launch_bounds__(256) void lif_fwd_kernel(
    const float4* __restrict__ x,
    const float*  __restrict__ tau_p,
    const float*  __restrict__ lamb_p,
    const float*  __restrict__ th_p,
    float4* __restrict__ out)
{
    const int tid = blockIdx.x * blockDim.x + threadIdx.x;   // 0 .. B*NV-1
    const int b   = tid / NV;
    const int n4  = tid - b * NV;

    const float sig  = 1.0f / (1.0f + expf(-tau_p[0]));      // 0.5 exact for tau_p=0
    const float lamb = lamb_p[0];
    const float th   = th_p[0];

    float4 last = make_float4(0.f, 0.f, 0.f, 0.f);
    size_t base = (size_t)b * LIF_T * NV + n4;

#pragma unroll 8
    for (int t = 0; t < LIF_T; ++t) {
        const size_t idx = base + (size_t)t * NV;
        float4 xv = x[idx];
        float4 sv;

        // lane .x
        {
            float u  = __fadd_rn(__fmul_rn(last.x, sig), xv.x);
            float s  = (u >= th) ? 1.0f : 0.0f;
            float nl = __fmul_rn(__fadd_rn(u, __fmul_rn(lamb, __fsub_rn(u, last.x))),
                                 __fsub_rn(1.0f, s));
            last.x = nl; sv.x = s;
        }
        // lane .y
        {
            float u  = __fadd_rn(__fmul_rn(last.y, sig), xv.y);
            float s  = (u >= th) ? 1.0f : 0.0f;
            float nl = __fmul_rn(__fadd_rn(u, __fmul_rn(lamb, __fsub_rn(u, last.y))),
                                 __fsub_rn(1.0f, s));
            last.y = nl; sv.y = s;
        }
        // lane .z
        {
            float u  = __fadd_rn(__fmul_rn(last.z, sig), xv.z);
            float s  = (u >= th) ? 1.0f : 0.0f;
            float nl = __fmul_rn(__fadd_rn(u, __fmul_rn(lamb, __fsub_rn(u, last.z))),
                                 __fsub_rn(1.0f, s));
            last.z = nl; sv.z = s;
        }
        // lane .w
        {
            float u  = __fadd_rn(__fmul_rn(last.w, sig), xv.w);
            float s  = (u >= th) ? 1.0f : 0.0f;
            float nl = __fmul_rn(__fadd_rn(u, __fmul_rn(lamb, __fsub_rn(u, last.w))),
                                 __fsub_rn(1.0f, s));
            last.w = nl; sv.w = s;
        }

        out[idx] = sv;
    }
}

extern "C" void kernel_launch(void* const* d_in, const int* in_sizes, int n_in,
                              void* d_out, int out_size, void* d_ws, size_t ws_size,
                              hipStream_t stream) {
    (void)in_sizes; (void)n_in; (void)out_size; (void)d_ws; (void)ws_size;

    const float4* x     = (const float4*)d_in[0];
    const float*  tau_p = (const float*)d_in[1];
    const float*  lamb  = (const float*)d_in[2];
    const float*  th    = (const float*)d_in[3];
    float4*       out   = (float4*)d_out;

    const int total_threads = LIF_B * NV;            // 131072
    const int block = 256;
    const int grid  = total_threads / block;         // 512

    lif_fwd_kernel<<<grid, block, 0, stream>>>(x, tau_p, lamb, th, out);
}

// Round 2
// 234.762 us; speedup vs baseline: 1.0372x; 1.0372x over previous
//
#include <hip/hip_runtime.h>

// Parametric LIF forward (spike output only).
// x: [B=64, T=64, N=8192] fp32.  out: same shape, values in {0,1}.
// Recurrence per (b,n):  u = last*sig + x[t];  s = (u >= th);
//                        last = (u + lamb*(u-last)) * (1-s)
//
// R1 post-mortem: float4-per-thread -> only 8 waves/CU (2/SIMD), latency-bound
// at 2.35 TB/s. R2: float2-per-thread (16 waves/CU), explicit 16-deep load
// batching for MLP, nontemporal stores to preserve L3 for x.
// All FP ops via *_rn intrinsics: forbid FMA contraction, match numpy bitwise
// (output is {0,1}; any spike flip = absmax 1.0).

#define LIF_B 64
#define LIF_T 64
#define LIF_N 8192
#define NV2 (LIF_N / 2)   // float2s per row = 4096
#define UNROLL 16

typedef float f2 __attribute__((ext_vector_type(2)));

__global__ __launch_bounds__(256) void lif_fwd_kernel(
    const f2* __restrict__ x,
    const float* __restrict__ tau_p,
    const float* __restrict__ lamb_p,
    const float* __restrict__ th_p,
    f2* __restrict__ out)
{
    const int tid = blockIdx.x * blockDim.x + threadIdx.x;   // 0 .. B*NV2-1
    const int b   = tid / NV2;
    const int n2  = tid - b * NV2;

    const float sig  = 1.0f / (1.0f + expf(-tau_p[0]));      // 0.5 exact for tau_p=0
    const float lamb = lamb_p[0];
    const float th   = th_p[0];

    float lx = 0.0f, ly = 0.0f;                              // carried state
    const size_t base = (size_t)b * LIF_T * NV2 + n2;

    for (int tb = 0; tb < LIF_T; tb += UNROLL) {
        f2 xv[UNROLL];
        // Batch all loads first -> UNROLL outstanding loads per wave.
#pragma unroll
        for (int i = 0; i < UNROLL; ++i) {
            xv[i] = x[base + (size_t)(tb + i) * NV2];
        }
        // Then the dependent recurrence + NT stores.
#pragma unroll
        for (int i = 0; i < UNROLL; ++i) {
            f2 sv;
            {
                float u  = __fadd_rn(__fmul_rn(lx, sig), xv[i].x);
                float s  = (u >= th) ? 1.0f : 0.0f;
                lx = __fmul_rn(__fadd_rn(u, __fmul_rn(lamb, __fsub_rn(u, lx))),
                               __fsub_rn(1.0f, s));
                sv.x = s;
            }
            {
                float u  = __fadd_rn(__fmul_rn(ly, sig), xv[i].y);
                float s  = (u >= th) ? 1.0f : 0.0f;
                ly = __fmul_rn(__fadd_rn(u, __fmul_rn(lamb, __fsub_rn(u, ly))),
                               __fsub_rn(1.0f, s));
                sv.y = s;
            }
            __builtin_nontemporal_store(sv, &out[base + (size_t)(tb + i) * NV2]);
        }
    }
}

extern "C" void kernel_launch(void* const* d_in, const int* in_sizes, int n_in,
                              void* d_out, int out_size, void* d_ws, size_t ws_size,
                              hipStream_t stream) {
    (void)in_sizes; (void)n_in; (void)out_size; (void)d_ws; (void)ws_size;

    const f2*    x     = (const f2*)d_in[0];
    const float* tau_p = (const float*)d_in[1];
    const float* lamb  = (const float*)d_in[2];
    const float* th    = (const float*)d_in[3];
    f2*          out   = (f2*)d_out;

    const int total_threads = LIF_B * NV2;           // 262144
    const int block = 256;
    const int grid  = total_threads / block;         // 1024

    lif_fwd_kernel<<<grid, block, 0, stream>>>(x, tau_p, lamb, th, out);
}

// Round 3
// 233.805 us; speedup vs baseline: 1.0415x; 1.0041x over previous
//
#include <hip/hip_runtime.h>

// Parametric LIF forward (spike output only).
// x: [B=64, T=64, N=8192] fp32.  out: same shape, values in {0,1}.
// Recurrence per (b,n):  u = last*sig + x[t];  s = (u >= th);
//                        last = (u + lamb*(u-last)) * (1-s)
//
// R2 post-mortem: interleaved load/compute/store ribbon -> stores are OLDER
// than next batch's loads in the vmcnt FIFO, so every compute-side
// s_waitcnt also drains store acks => batch-boundary serialization (~76us,
// 5.7 B/cyc/CU vs fill kernels' 10+). R3: register double-buffer software
// pipeline: issue batch k+1 loads BEFORE batch k stores. Loads then retire
// ahead of stores (in-order vmcnt), so compute waits never block on stores.
// All FP ops via *_rn intrinsics: forbid FMA contraction, match numpy bitwise
// (output is {0,1}; any spike flip = absmax 1.0).

#define LIF_B 64
#define LIF_T 64
#define LIF_N 8192
#define NV2 (LIF_N / 2)   // float2s per row = 4096
#define UN 8              // t-steps per pipeline stage
#define NSTAGE (LIF_T / UN)

typedef float f2 __attribute__((ext_vector_type(2)));

__global__ __launch_bounds__(256) void lif_fwd_kernel(
    const f2* __restrict__ x,
    const float* __restrict__ tau_p,
    const float* __restrict__ lamb_p,
    const float* __restrict__ th_p,
    f2* __restrict__ out)
{
    const int tid = blockIdx.x * blockDim.x + threadIdx.x;   // 0 .. B*NV2-1
    const int b   = tid / NV2;
    const int n2  = tid - b * NV2;

    const float sig  = 1.0f / (1.0f + expf(-tau_p[0]));      // 0.5 exact for tau_p=0
    const float lamb = lamb_p[0];
    const float th   = th_p[0];

    float lx = 0.0f, ly = 0.0f;                              // carried state
    const size_t base = (size_t)b * LIF_T * NV2 + n2;

    f2 cur[UN], nxt[UN];

    // Prologue: load stage 0.
#pragma unroll
    for (int i = 0; i < UN; ++i)
        cur[i] = x[base + (size_t)i * NV2];

#pragma unroll
    for (int k = 0; k < NSTAGE; ++k) {
        // 1) Prefetch stage k+1 FIRST (older than this stage's stores in the
        //    vmcnt FIFO -> compute waits next stage don't drain stores).
        if (k + 1 < NSTAGE) {
#pragma unroll
            for (int i = 0; i < UN; ++i)
                nxt[i] = x[base + (size_t)((k + 1) * UN + i) * NV2];
        }

        // 2) Compute + store stage k.
#pragma unroll
        for (int i = 0; i < UN; ++i) {
            f2 sv;
            {
                float u  = __fadd_rn(__fmul_rn(lx, sig), cur[i].x);
                float s  = (u >= th) ? 1.0f : 0.0f;
                lx = __fmul_rn(__fadd_rn(u, __fmul_rn(lamb, __fsub_rn(u, lx))),
                               __fsub_rn(1.0f, s));
                sv.x = s;
            }
            {
                float u  = __fadd_rn(__fmul_rn(ly, sig), cur[i].y);
                float s  = (u >= th) ? 1.0f : 0.0f;
                ly = __fmul_rn(__fadd_rn(u, __fmul_rn(lamb, __fsub_rn(u, ly))),
                               __fsub_rn(1.0f, s));
                sv.y = s;
            }
            __builtin_nontemporal_store(sv, &out[base + (size_t)(k * UN + i) * NV2]);
        }

        // 3) Rotate (register renames after full unroll).
#pragma unroll
        for (int i = 0; i < UN; ++i)
            cur[i] = nxt[i];
    }
}

extern "C" void kernel_launch(void* const* d_in, const int* in_sizes, int n_in,
                              void* d_out, int out_size, void* d_ws, size_t ws_size,
                              hipStream_t stream) {
    (void)in_sizes; (void)n_in; (void)out_size; (void)d_ws; (void)ws_size;

    const f2*    x     = (const f2*)d_in[0];
    const float* tau_p = (const float*)d_in[1];
    const float* lamb  = (const float*)d_in[2];
    const float* th    = (const float*)d_in[3];
    f2*          out   = (f2*)d_out;

    const int total_threads = LIF_B * NV2;           // 262144
    const int block = 256;
    const int grid  = total_threads / block;         // 1024

    lif_fwd_kernel<<<grid, block, 0, stream>>>(x, tau_p, lamb, th, out);
}